// Round 12
// baseline (217.388 us; speedup 1.0000x reference)
//
#include <hip/hip_runtime.h>

typedef __attribute__((ext_vector_type(8))) short bf16x8;
typedef __attribute__((ext_vector_type(4))) float f32x4;
typedef __attribute__((ext_vector_type(8))) unsigned short us8;

#define DEVI __device__ __forceinline__

// work-table upper bounds: sum_c ceil(m_c/64) <= E/64 + 64, times N-slices
#define MAXW2 1088   // (65536/64 + 64) * 1
#define MAXW3 640    // (16384/64 + 64) * 2
#define MAXW4 512    // (4096/64  + 64) * 4

// ---------- helpers ----------

DEVI unsigned enc_pool(float f) {
  unsigned u = __float_as_uint(f);
  return (u & 0x80000000u) ? ~u : (u | 0x80000000u);
}
DEVI float dec_pool(unsigned k) {
  if (k == 0u) return 0.0f;  // empty voxel -> 0
  return __uint_as_float((k & 0x80000000u) ? (k ^ 0x80000000u) : ~k);
}
DEVI float eluf(float x) { return x > 0.0f ? x : expm1f(x); }
DEVI unsigned short to_bf16(float f) {  // round-to-nearest-even
  unsigned u = __float_as_uint(f);
  return (unsigned short)((u + 0x7FFFu + ((u >> 16) & 1u)) >> 16);
}

DEVI int cell_of(const float* __restrict__ ps, int e) {
  int cell = 0;
#pragma unroll
  for (int d = 0; d < 3; ++d) {
    float v = ps[e * 3 + d] * 4.0f;
    float fl = fminf(fmaxf(floorf(v), 0.0f), 3.0f);
    cell |= ((int)fl) << (2 * d);
  }
  return cell;
}

// ---------- W -> bf16 fragment-ready permutation, vectorized (8 idx / thread) ----------
// P[idx]: idx=((kb*COUT+n)*4+g)*8+j, source W[(k*CIN + kb*32+g*8+j)*COUT + n]
__global__ __launch_bounds__(256) void sc_convw(
    const float* __restrict__ W2, const float* __restrict__ W3, const float* __restrict__ W4,
    unsigned short* __restrict__ P2, unsigned short* __restrict__ P3, unsigned short* __restrict__ P4) {
  int u = blockIdx.x * 256 + threadIdx.x;   // us8-unit id
  const int U2 = 32000, U3 = 128000;        // 125*CIN*COUT/8 per level
  const float* W; unsigned short* P; int CIN, COUT;
  if (u < U2)           { W = W2; P = P2; CIN = 32;  COUT = 64;  }
  else if (u < U2 + U3) { u -= U2; W = W3; P = P3; CIN = 64;  COUT = 128; }
  else                  { u -= U2 + U3; W = W4; P = P4; CIN = 128; COUT = 256; }
  int MAT8 = CIN * COUT / 8;
  int k = u / MAT8, off8 = u % MAT8;
  int g = off8 & 3;
  int rem = off8 >> 2;
  int n = rem % COUT, kb = rem / COUT;
  const float* ws = W + ((size_t)k * CIN + kb * 32 + g * 8) * COUT + n;
  us8 o;
#pragma unroll
  for (int j = 0; j < 8; ++j) o[j] = to_bf16(ws[(size_t)j * COUT]);
  *(us8*)(P + (size_t)u * 8) = o;
}

// ---------- fused prep: count(L2..L4) ∪ conv1-C ----------
// conv1-C: C[dst][k] += bw_corner * x[src]  (8 atomics/edge instead of 32)
__global__ __launch_bounds__(256) void sc_prep(
    const int* __restrict__ ei2, const float* __restrict__ ps2,
    const int* __restrict__ ei3, const float* __restrict__ ps3,
    const int* __restrict__ ei4, const float* __restrict__ ps4,
    unsigned* __restrict__ bc2, unsigned* __restrict__ bc3, unsigned* __restrict__ bc4,
    unsigned* __restrict__ deg2, unsigned* __restrict__ deg3, unsigned* __restrict__ deg4,
    const float* __restrict__ x, const int* __restrict__ ei1, const float* __restrict__ ps1,
    float* __restrict__ C, unsigned* __restrict__ deg1) {
  __shared__ unsigned hist[64];
  int b = blockIdx.x, t = threadIdx.x;
  if (b < 336) {  // count arm (256 edges/block)
    const int* ei; const float* ps; unsigned *bc, *deg; int E, blk, NB;
    if (b < 256)      { ei = ei2; ps = ps2; bc = bc2; deg = deg2; E = 65536; blk = b;       NB = 256; }
    else if (b < 320) { ei = ei3; ps = ps3; bc = bc3; deg = deg3; E = 16384; blk = b - 256; NB = 64;  }
    else              { ei = ei4; ps = ps4; bc = bc4; deg = deg4; E = 4096;  blk = b - 320; NB = 16;  }
    if (t < 64) hist[t] = 0;
    __syncthreads();
    int e = blk * 256 + t;
    atomicAdd(&hist[cell_of(ps, e)], 1u);
    atomicAdd(deg + ei[E + e], 1u);
    __syncthreads();
    if (t < 64) bc[(size_t)t * NB + blk] = hist[t];
    return;
  }
  b -= 336;
  // conv1-C arm: 8192 blocks; thread = (edge, corner)
  int tid = b * 256 + t;       // 0 .. 2097151
  int e = tid >> 3, s = tid & 7;
  int src = ei1[e], dst = ei1[262144 + e];
  float f[3]; int lo[3];
#pragma unroll
  for (int d = 0; d < 3; ++d) {
    float v = ps1[e * 3 + d] * 4.0f;
    float fl = fminf(fmaxf(floorf(v), 0.0f), 3.0f);
    lo[d] = (int)fl;
    f[d] = v - fl;
  }
  int c0 = s & 1, c1 = (s >> 1) & 1, c2 = s >> 2;
  float bw = (c0 ? f[0] : 1.0f - f[0]) * (c1 ? f[1] : 1.0f - f[1]) *
             (c2 ? f[2] : 1.0f - f[2]);
  int k = (lo[0] + c0) + 5 * (lo[1] + c1) + 25 * (lo[2] + c2);
  atomicAdd(C + (size_t)dst * 128 + k, bw * x[src]);
  if (s == 0) atomicAdd(deg1 + dst, 1u);
}

// ---------- scan: hierarchical, 1 block x 1024 threads ----------
__global__ __launch_bounds__(1024) void sc_scan_all(
    const unsigned* __restrict__ bc2, const unsigned* __restrict__ bc3,
    const unsigned* __restrict__ bc4,
    unsigned* __restrict__ bb2, unsigned* __restrict__ bb3, unsigned* __restrict__ bb4,
    unsigned* __restrict__ cnt2, unsigned* __restrict__ cnt3, unsigned* __restrict__ cnt4,
    unsigned* __restrict__ base2, unsigned* __restrict__ base3, unsigned* __restrict__ base4,
    unsigned* __restrict__ wt2, unsigned* __restrict__ wt3, unsigned* __restrict__ wt4) {
  __shared__ unsigned tot[3][64];
  __shared__ unsigned sbs[3][64];
  int t = threadIdx.x, w = t >> 6, lane = t & 63;
  // ---- phase 1: 16 waves, intra-cell block prefixes + cell totals ----
#pragma unroll
  for (int lvl = 0; lvl < 3; ++lvl) {
    const unsigned* bc = lvl == 0 ? bc2 : lvl == 1 ? bc3 : bc4;
    unsigned* bb = lvl == 0 ? bb2 : lvl == 1 ? bb3 : bb4;
    int NB = lvl == 0 ? 256 : lvl == 1 ? 64 : 16;
    for (int c = w; c < 64; c += 16) {
      unsigned cellsum = 0;
      for (int sub = 0; sub * 64 < NB; ++sub) {
        int bi = sub * 64 + lane;
        unsigned v = (bi < NB) ? bc[c * NB + bi] : 0u;
        int incl = (int)v;
#pragma unroll
        for (int d = 1; d < 64; d <<= 1) {
          int tv = __shfl_up(incl, d);
          if (lane >= d) incl += tv;
        }
        if (bi < NB) bb[c * NB + bi] = cellsum + (unsigned)incl - v;
        cellsum += (unsigned)__shfl(incl, 63);
      }
      if (lane == 0) tot[lvl][c] = cellsum;
    }
  }
  __syncthreads();
  // ---- phase 2: per-level 64-cell scan + work table ----
  if (w < 3) {
    unsigned* cnt = w == 0 ? cnt2 : w == 1 ? cnt3 : cnt4;
    unsigned* bs  = w == 0 ? base2 : w == 1 ? base3 : base4;
    unsigned* wt  = w == 0 ? wt2 : w == 1 ? wt3 : wt4;
    int NSP  = w == 0 ? 1 : w == 1 ? 2 : 4;
    int MAXW = w == 0 ? MAXW2 : w == 1 ? MAXW3 : MAXW4;
    unsigned v = tot[w][lane];
    int incl = (int)v;
#pragma unroll
    for (int d = 1; d < 64; d <<= 1) {
      int tv = __shfl_up(incl, d);
      if (lane >= d) incl += tv;
    }
    unsigned excl = (unsigned)incl - v;
    sbs[w][lane] = excl;
    cnt[lane] = v;
    bs[lane] = excl;
    int nch = (int)((v + 63) >> 6);
    int cscan = nch;
#pragma unroll
    for (int d = 1; d < 64; d <<= 1) {
      int tv = __shfl_up(cscan, d);
      if (lane >= d) cscan += tv;
    }
    int cbase = cscan - nch;
    int CT = __shfl(cscan, 63);
    for (int ch = 0; ch < nch; ++ch)
      for (int ns = 0; ns < NSP; ++ns)
        wt[(cbase + ch) * NSP + ns] = ((unsigned)lane << 16) | ((unsigned)ch << 8) | (unsigned)ns;
    for (int i = CT * NSP + lane; i < MAXW; i += 64) wt[i] = 0xFFFFFFFFu;
  }
  __syncthreads();
  // ---- phase 3: add cell base into bb ----
  for (int i = t; i < 64 * 256; i += 1024) bb2[i] += sbs[0][i >> 8];
  for (int i = t; i < 64 * 64; i += 1024)  bb3[i] += sbs[1][i >> 6];
  for (int i = t; i < 64 * 16; i += 1024)  bb4[i] += sbs[2][i >> 4];
}

// ---------- fused rank(L2..L4) ∪ finpool level-1 (agg1 = C @ W1 on the fly) ----------
__global__ __launch_bounds__(256) void sc_rank_fin1(
    const int* __restrict__ ei2, const float* __restrict__ ps2,
    const int* __restrict__ ei3, const float* __restrict__ ps3,
    const int* __restrict__ ei4, const float* __restrict__ ps4,
    const unsigned* __restrict__ bb2, const unsigned* __restrict__ bb3,
    const unsigned* __restrict__ bb4,
    int* __restrict__ eid2, int* __restrict__ eid3, int* __restrict__ eid4,
    int* __restrict__ dst2, int* __restrict__ dst3, int* __restrict__ dst4,
    const float* __restrict__ x, const float* __restrict__ C,
    const float* __restrict__ W1,
    const unsigned* __restrict__ deg1, const float* __restrict__ root1,
    const float* __restrict__ b1, const int* __restrict__ cl1,
    unsigned* __restrict__ pe1) {
  __shared__ unsigned hist[64];
  __shared__ float sW1[4000];  // 125 x 32
  int b = blockIdx.x, t = threadIdx.x;
  if (b < 336) {  // rank arm (mirrors sc_prep count-arm block mapping)
    const int* ei; const float* ps; const unsigned* bb; int *eid, *dsts; int E, blk, NB;
    if (b < 256)      { ei = ei2; ps = ps2; bb = bb2; eid = eid2; dsts = dst2; E = 65536; blk = b;       NB = 256; }
    else if (b < 320) { ei = ei3; ps = ps3; bb = bb3; eid = eid3; dsts = dst3; E = 16384; blk = b - 256; NB = 64;  }
    else              { ei = ei4; ps = ps4; bb = bb4; eid = eid4; dsts = dst4; E = 4096;  blk = b - 320; NB = 16;  }
    if (t < 64) hist[t] = 0;
    __syncthreads();
    int e = blk * 256 + t;
    int cell = cell_of(ps, e);
    unsigned r = atomicAdd(&hist[cell], 1u);
    int p = (int)(bb[cell * NB + blk] + r);
    eid[p] = e;
    dsts[p] = ei[E + e];
    return;
  }
  b -= 336;
  // finpool1 arm: agg = C[n] @ W1; h = elu(agg/deg + x*root + b) -> atomicMax pool
  for (int i = t; i < 4000; i += 256) sW1[i] = W1[i];
  __syncthreads();
  int tid = b * 256 + t;  // over 32768*32
  int n = tid >> 5, o = tid & 31;
  const float* Cn = C + (size_t)n * 128;
  float acc = 0.f;
#pragma unroll 5
  for (int k = 0; k < 125; ++k) acc += Cn[k] * sW1[k * 32 + o];
  unsigned dv = deg1[n];
  acc = acc / (float)(dv ? dv : 1u) + b1[o] + x[n] * root1[o];
  atomicMax(pe1 + (size_t)cl1[n] * 32 + o, enc_pool(eluf(acc)));
}

// ---------- fused finalize + pool (levels 2..4) ----------
template <int CIN, int COUT>
__global__ void sc_finpool(const unsigned* __restrict__ xenc, const float* __restrict__ agg,
                           const unsigned* __restrict__ deg, const float* __restrict__ root,
                           const float* __restrict__ bias, const int* __restrict__ cluster,
                           unsigned* __restrict__ pe_out, int N) {
  int tid = blockIdx.x * blockDim.x + threadIdx.x;
  if (tid >= N * COUT) return;
  int n = tid / COUT, o = tid % COUT;
  unsigned dv = deg[n];
  float acc = agg[tid] / (float)(dv ? dv : 1u) + bias[o];
#pragma unroll 4
  for (int c = 0; c < CIN; ++c)
    acc += dec_pool(xenc[n * CIN + c]) * root[c * COUT + o];
  atomicMax(pe_out + (size_t)cluster[n] * COUT + o, enc_pool(eluf(acc)));
}

// ---------- GEMM: dense work table, N-split, A-tile built from pe, B staged from Wp ----------
// entry: cell<<16 | chunk<<8 | nslice. Block: 64 rows x 64 cols, full K.
template <int CIN, int COUT, int NSP>
DEVI void gemm_impl(const int* __restrict__ ei, const float* __restrict__ ps,
                    const unsigned* __restrict__ xenc, const int* __restrict__ eid,
                    const unsigned short* __restrict__ Wp,
                    const unsigned* __restrict__ cnt, const unsigned* __restrict__ base,
                    const unsigned* __restrict__ wtab, const int* __restrict__ dsts,
                    float* __restrict__ agg) {
  constexpr int K = 8 * CIN;
  constexpr int NCOL = COUT / NSP;   // 64 for all levels
  constexpr int NT = NCOL / 16;      // 4
  constexpr int UPT = NCOL / 32;     // 2
  constexpr int NPASS = K / 64;
  __shared__ __attribute__((aligned(16))) unsigned char lds[2 * NCOL * 80];
  __shared__ __attribute__((aligned(16))) unsigned short ldsA[64][72];
  __shared__ float s_bw[64][8];
  __shared__ int s_src[64];
  unsigned u = wtab[blockIdx.x];
  if (u == 0xFFFFFFFFu) return;
  int cell = u >> 16, chunk = (u >> 8) & 255, nsl = u & 255;
  int n0 = nsl * NCOL;
  int m = (int)cnt[cell], cb = (int)base[cell];
  int row0 = chunk * 64;
  int tid = threadIdx.x;
  int wv = tid >> 6, lane = tid & 63, g4 = lane >> 4, ln = lane & 15;
  int lo0 = cell & 3, lo1 = (cell >> 2) & 3, lo2 = cell >> 4;
  // block init: per-row edge basis + src (64 rows, clamped)
  if (tid < 64) {
    int ridx = cb + min(row0 + tid, m - 1);
    int e = eid[ridx];
    s_src[tid] = ei[e];
    float f[3];
#pragma unroll
    for (int d = 0; d < 3; ++d) {
      float v = ps[e * 3 + d] * 4.0f;
      float fl = fminf(fmaxf(floorf(v), 0.0f), 3.0f);
      f[d] = v - fl;
    }
#pragma unroll
    for (int s = 0; s < 8; ++s) {
      int b0 = s & 1, b1 = (s >> 1) & 1, b2 = (s >> 2) & 1;
      s_bw[tid][s] = (b0 ? f[0] : 1.0f - f[0]) * (b1 ? f[1] : 1.0f - f[1]) *
                     (b2 ? f[2] : 1.0f - f[2]);
    }
  }
  f32x4 acc[NT];
#pragma unroll
  for (int t = 0; t < NT; ++t) acc[t] = (f32x4){0.f, 0.f, 0.f, 0.f};
  for (int pass = 0; pass < NPASS; ++pass) {
    int k0 = pass * 64;
    __syncthreads();
    // stage B slice from fragment-ready Wp (one us8 load per unit)
#pragma unroll
    for (int i = 0; i < UPT; ++i) {
      int u16 = tid + i * 256;
      int grp = u16 / (4 * NCOL), win = u16 % (4 * NCOL);
      int kg = k0 + grp * 32;
      int s = kg / CIN, kb = (kg % CIN) >> 5;
      int b0 = s & 1, b1 = (s >> 1) & 1, b2 = (s >> 2) & 1;
      int mat = (lo0 + b0) + 5 * (lo1 + b1) + 25 * (lo2 + b2);
      const us8* srcp = (const us8*)(Wp + (size_t)mat * (CIN * COUT) +
                                     (size_t)(kb * COUT * 4 + n0 * 4 + win) * 8);
      int r = grp * NCOL + (win >> 2), gg = win & 3;
      *(us8*)(lds + r * 80 + gg * 16) = *srcp;
    }
    // stage A tile: 64 rows x 64 k, gathered from pe + bw-scaled
    {
      int r = tid >> 2, q = tid & 3;
      int kg = k0 + q * 16;
      int sidx = kg / CIN;
      int c0 = kg & (CIN - 1);
      float bwv = s_bw[r][sidx];
      const uint4* xp = (const uint4*)(xenc + (size_t)s_src[r] * CIN + c0);
      uint4 xa = xp[0], xb = xp[1];
      us8 o0;
      o0[0] = to_bf16(bwv * dec_pool(xa.x)); o0[1] = to_bf16(bwv * dec_pool(xa.y));
      o0[2] = to_bf16(bwv * dec_pool(xa.z)); o0[3] = to_bf16(bwv * dec_pool(xa.w));
      o0[4] = to_bf16(bwv * dec_pool(xb.x)); o0[5] = to_bf16(bwv * dec_pool(xb.y));
      o0[6] = to_bf16(bwv * dec_pool(xb.z)); o0[7] = to_bf16(bwv * dec_pool(xb.w));
      uint4 xc = xp[2], xd = xp[3];
      us8 o1;
      o1[0] = to_bf16(bwv * dec_pool(xc.x)); o1[1] = to_bf16(bwv * dec_pool(xc.y));
      o1[2] = to_bf16(bwv * dec_pool(xc.z)); o1[3] = to_bf16(bwv * dec_pool(xc.w));
      o1[4] = to_bf16(bwv * dec_pool(xd.x)); o1[5] = to_bf16(bwv * dec_pool(xd.y));
      o1[6] = to_bf16(bwv * dec_pool(xd.z)); o1[7] = to_bf16(bwv * dec_pool(xd.w));
      *(us8*)&ldsA[r][q * 16] = o0;
      *(us8*)&ldsA[r][q * 16 + 8] = o1;
    }
    __syncthreads();
#pragma unroll
    for (int kk = 0; kk < 2; ++kk) {
      bf16x8 af = *(const bf16x8*)&ldsA[wv * 16 + ln][kk * 32 + g4 * 8];
#pragma unroll
      for (int t = 0; t < NT; ++t) {
        int r = kk * NCOL + t * 16 + ln;
        bf16x8 bfr = *(const bf16x8*)(lds + r * 80 + g4 * 16);
        acc[t] = __builtin_amdgcn_mfma_f32_16x16x32_bf16(af, bfr, acc[t], 0, 0, 0);
      }
    }
  }
  int row_b = row0 + wv * 16 + g4 * 4;
  int dstv[4];
#pragma unroll
  for (int r4 = 0; r4 < 4; ++r4)
    dstv[r4] = (row_b + r4 < m) ? dsts[cb + row_b + r4] : -1;
#pragma unroll
  for (int t = 0; t < NT; ++t) {
#pragma unroll
    for (int r4 = 0; r4 < 4; ++r4) {
      if (dstv[r4] >= 0)
        atomicAdd(agg + (size_t)dstv[r4] * COUT + n0 + t * 16 + ln, acc[t][r4]);
    }
  }
}

__global__ __launch_bounds__(256) void sc_gemm_l2(
    const int* ei, const float* ps, const unsigned* xenc, const int* eid,
    const unsigned short* Wp, const unsigned* cnt, const unsigned* base,
    const unsigned* wtab, const int* dsts, float* agg) {
  gemm_impl<32, 64, 1>(ei, ps, xenc, eid, Wp, cnt, base, wtab, dsts, agg);
}
__global__ __launch_bounds__(256) void sc_gemm_l3(
    const int* ei, const float* ps, const unsigned* xenc, const int* eid,
    const unsigned short* Wp, const unsigned* cnt, const unsigned* base,
    const unsigned* wtab, const int* dsts, float* agg) {
  gemm_impl<64, 128, 2>(ei, ps, xenc, eid, Wp, cnt, base, wtab, dsts, agg);
}
__global__ __launch_bounds__(256) void sc_gemm_l4(
    const int* ei, const float* ps, const unsigned* xenc, const int* eid,
    const unsigned short* Wp, const unsigned* cnt, const unsigned* base,
    const unsigned* wtab, const int* dsts, float* agg) {
  gemm_impl<128, 256, 4>(ei, ps, xenc, eid, Wp, cnt, base, wtab, dsts, agg);
}

// ---------- FC head ----------
__global__ void sc_fc1(const unsigned* __restrict__ xenc, const float* __restrict__ w,
                       float* __restrict__ out) {
  __shared__ float sx[8][32];
  int t = threadIdx.x;
  int j = blockIdx.x * 256 + t;          // 0..511
  int c0 = blockIdx.y * 32;              // 64 chunks
  {
    int b = t >> 5, c = t & 31;
    sx[b][c] = dec_pool(xenc[b * 2048 + c0 + c]);
  }
  __syncthreads();
  float acc[8];
#pragma unroll
  for (int b = 0; b < 8; ++b) acc[b] = 0.f;
#pragma unroll 4
  for (int cc = 0; cc < 32; ++cc) {
    float wv = w[(size_t)(c0 + cc) * 512 + j];
#pragma unroll
    for (int b = 0; b < 8; ++b) acc[b] += sx[b][cc] * wv;
  }
#pragma unroll
  for (int b = 0; b < 8; ++b) atomicAdd(out + b * 512 + j, acc[b]);
}

__global__ void sc_fc2(const float* __restrict__ h, const float* __restrict__ b1,
                       const float* __restrict__ w2, const float* __restrict__ b2,
                       float* __restrict__ out) {
  int b = blockIdx.x;
  int lane = threadIdx.x;
  float part[10];
#pragma unroll
  for (int o = 0; o < 10; ++o) part[o] = 0.f;
  for (int k = 0; k < 8; ++k) {
    int c = k * 64 + lane;
    float v = eluf(h[b * 512 + c] + b1[c]);
#pragma unroll
    for (int o = 0; o < 10; ++o) part[o] += v * w2[c * 10 + o];
  }
#pragma unroll
  for (int o = 0; o < 10; ++o) {
#pragma unroll
    for (int d = 32; d > 0; d >>= 1) part[o] += __shfl_down(part[o], d);
  }
  if (lane == 0) {
    float z[10], mx = -1e30f;
#pragma unroll
    for (int o = 0; o < 10; ++o) { z[o] = part[o] + b2[o]; mx = fmaxf(mx, z[o]); }
    float sum = 0.f;
#pragma unroll
    for (int o = 0; o < 10; ++o) sum += expf(z[o] - mx);
    float lse = mx + logf(sum);
#pragma unroll
    for (int o = 0; o < 10; ++o) out[b * 10 + o] = z[o] - lse;
  }
}

// ---------- host ----------
extern "C" void kernel_launch(void* const* d_in, const int* in_sizes, int n_in,
                              void* d_out, int out_size, void* d_ws, size_t ws_size,
                              hipStream_t stream) {
  (void)in_sizes; (void)n_in; (void)out_size; (void)ws_size;
  const float* x    = (const float*)d_in[0];
  const int*   ei1  = (const int*)d_in[1];
  const float* ps1  = (const float*)d_in[2];
  const int*   cl1  = (const int*)d_in[3];
  const int*   ei2  = (const int*)d_in[4];
  const float* ps2  = (const float*)d_in[5];
  const int*   cl2  = (const int*)d_in[6];
  const int*   ei3  = (const int*)d_in[7];
  const float* ps3  = (const float*)d_in[8];
  const int*   cl3  = (const int*)d_in[9];
  const int*   ei4  = (const int*)d_in[10];
  const float* ps4  = (const float*)d_in[11];
  const int*   cl4  = (const int*)d_in[12];
  const float* W1   = (const float*)d_in[13];
  const float* root1= (const float*)d_in[14];
  const float* b1   = (const float*)d_in[15];
  const float* W2   = (const float*)d_in[16];
  const float* root2= (const float*)d_in[17];
  const float* b2   = (const float*)d_in[18];
  const float* W3   = (const float*)d_in[19];
  const float* root3= (const float*)d_in[20];
  const float* b3   = (const float*)d_in[21];
  const float* W4   = (const float*)d_in[22];
  const float* root4= (const float*)d_in[23];
  const float* b4   = (const float*)d_in[24];
  const float* fc1w = (const float*)d_in[25];
  const float* fc1b = (const float*)d_in[26];
  const float* fc2w = (const float*)d_in[27];
  const float* fc2b = (const float*)d_in[28];
  float* out = (float*)d_out;

  char* ws = (char*)d_ws;
  size_t off = 0;
  auto alloc = [&](size_t bytes) -> void* {
    void* p = ws + off;
    off = (off + bytes + 255) & ~(size_t)255;
    return p;
  };
  // ---- zero-init region (one memset) ----
  float*    C    = (float*)alloc(32768ull * 128 * 4);   // conv1 coefficient matrix
  float*    agg2 = (float*)alloc(8192ull * 64 * 4);
  float*    agg3 = (float*)alloc(2048ull * 128 * 4);
  float*    agg4 = (float*)alloc(512ull * 256 * 4);
  unsigned* deg1 = (unsigned*)alloc(32768ull * 4);
  unsigned* deg2 = (unsigned*)alloc(8192ull * 4);
  unsigned* deg3 = (unsigned*)alloc(2048ull * 4);
  unsigned* deg4 = (unsigned*)alloc(512ull * 4);
  unsigned* pe1  = (unsigned*)alloc(8192ull * 32 * 4);
  unsigned* pe2  = (unsigned*)alloc(2048ull * 64 * 4);
  unsigned* pe3  = (unsigned*)alloc(512ull * 128 * 4);
  unsigned* pe4  = (unsigned*)alloc(64ull * 256 * 4);
  float*    fc1o = (float*)alloc(8ull * 512 * 4);
  size_t zero_bytes = off;
  // ---- non-zero region (fully written each call) ----
  unsigned* bc2   = (unsigned*)alloc(64ull * 256 * 4);
  unsigned* bc3   = (unsigned*)alloc(64ull * 64 * 4);
  unsigned* bc4   = (unsigned*)alloc(64ull * 16 * 4);
  unsigned* bb2   = (unsigned*)alloc(64ull * 256 * 4);
  unsigned* bb3   = (unsigned*)alloc(64ull * 64 * 4);
  unsigned* bb4   = (unsigned*)alloc(64ull * 16 * 4);
  unsigned* cnt2  = (unsigned*)alloc(64 * 4);
  unsigned* cnt3  = (unsigned*)alloc(64 * 4);
  unsigned* cnt4  = (unsigned*)alloc(64 * 4);
  unsigned* base2 = (unsigned*)alloc(64 * 4);
  unsigned* base3 = (unsigned*)alloc(64 * 4);
  unsigned* base4 = (unsigned*)alloc(64 * 4);
  unsigned* wt2   = (unsigned*)alloc(MAXW2 * 4);
  unsigned* wt3   = (unsigned*)alloc(MAXW3 * 4);
  unsigned* wt4   = (unsigned*)alloc(MAXW4 * 4);
  int* eid2 = (int*)alloc(65536ull * 4);
  int* eid3 = (int*)alloc(16384ull * 4);
  int* eid4 = (int*)alloc(4096ull * 4);
  int* dst2 = (int*)alloc(65536ull * 4);
  int* dst3 = (int*)alloc(16384ull * 4);
  int* dst4 = (int*)alloc(4096ull * 4);
  unsigned short* Wp2 = (unsigned short*)alloc(125ull * 32 * 64 * 2);
  unsigned short* Wp3 = (unsigned short*)alloc(125ull * 64 * 128 * 2);
  unsigned short* Wp4 = (unsigned short*)alloc(125ull * 128 * 256 * 2);

  hipMemsetAsync(d_ws, 0, zero_bytes, stream);
  // fragment-ready bf16 weights (672000 us8 units)
  sc_convw<<<2625, 256, 0, stream>>>(W2, W3, W4, Wp2, Wp3, Wp4);
  // prep: count ∪ conv1-C  (336 + 8192 blocks)
  sc_prep<<<8528, 256, 0, stream>>>(ei2, ps2, ei3, ps3, ei4, ps4,
                                    bc2, bc3, bc4, deg2, deg3, deg4,
                                    x, ei1, ps1, C, deg1);
  sc_scan_all<<<1, 1024, 0, stream>>>(bc2, bc3, bc4, bb2, bb3, bb4,
                                      cnt2, cnt3, cnt4, base2, base3, base4,
                                      wt2, wt3, wt4);
  // rank ∪ finpool1  (336 + 4096 blocks)
  sc_rank_fin1<<<4432, 256, 0, stream>>>(ei2, ps2, ei3, ps3, ei4, ps4,
                                         bb2, bb3, bb4, eid2, eid3, eid4,
                                         dst2, dst3, dst4,
                                         x, C, W1, deg1, root1, b1, cl1, pe1);

  // ---- level 2 ----
  sc_gemm_l2<<<MAXW2, 256, 0, stream>>>(ei2, ps2, pe1, eid2, Wp2, cnt2, base2, wt2, dst2, agg2);
  sc_finpool<32, 64><<<2048, 256, 0, stream>>>(pe1, agg2, deg2, root2, b2, cl2, pe2, 8192);

  // ---- level 3 ----
  sc_gemm_l3<<<MAXW3, 256, 0, stream>>>(ei3, ps3, pe2, eid3, Wp3, cnt3, base3, wt3, dst3, agg3);
  sc_finpool<64, 128><<<1024, 256, 0, stream>>>(pe2, agg3, deg3, root3, b3, cl3, pe3, 2048);

  // ---- level 4 ----
  sc_gemm_l4<<<MAXW4, 256, 0, stream>>>(ei4, ps4, pe3, eid4, Wp4, cnt4, base4, wt4, dst4, agg4);
  sc_finpool<128, 256><<<512, 256, 0, stream>>>(pe3, agg4, deg4, root4, b4, cl4, pe4, 512);

  // ---- FC head ----
  sc_fc1<<<dim3(2, 64), 256, 0, stream>>>(pe4, fc1w, fc1o);
  sc_fc2<<<8, 64, 0, stream>>>(fc1o, fc1b, fc2w, fc2b, out);
}

// Round 13
// 188.347 us; speedup vs baseline: 1.1542x; 1.1542x over previous
//
#include <hip/hip_runtime.h>

typedef __attribute__((ext_vector_type(8))) short bf16x8;
typedef __attribute__((ext_vector_type(4))) float f32x4;
typedef __attribute__((ext_vector_type(8))) unsigned short us8;

#define DEVI __device__ __forceinline__

// work-table upper bounds: sum_c ceil(m_c/64) <= E/64 + 64, times N-slices
#define MAXW2 1088   // (65536/64 + 64) * 1
#define MAXW3 640    // (16384/64 + 64) * 2
#define MAXW4 512    // (4096/64  + 64) * 4

// ---------- helpers ----------

DEVI unsigned enc_pool(float f) {
  unsigned u = __float_as_uint(f);
  return (u & 0x80000000u) ? ~u : (u | 0x80000000u);
}
DEVI float dec_pool(unsigned k) {
  if (k == 0u) return 0.0f;  // empty voxel -> 0
  return __uint_as_float((k & 0x80000000u) ? (k ^ 0x80000000u) : ~k);
}
DEVI float eluf(float x) { return x > 0.0f ? x : expm1f(x); }
DEVI unsigned short to_bf16(float f) {  // round-to-nearest-even
  unsigned u = __float_as_uint(f);
  return (unsigned short)((u + 0x7FFFu + ((u >> 16) & 1u)) >> 16);
}

DEVI int cell_of(const float* __restrict__ ps, int e) {
  int cell = 0;
#pragma unroll
  for (int d = 0; d < 3; ++d) {
    float v = ps[e * 3 + d] * 4.0f;
    float fl = fminf(fmaxf(floorf(v), 0.0f), 3.0f);
    cell |= ((int)fl) << (2 * d);
  }
  return cell;
}

// ---------- W -> bf16 fragment-ready permutation, vectorized (8 elems / thread) ----------
__global__ __launch_bounds__(256) void sc_convw(
    const float* __restrict__ W2, const float* __restrict__ W3, const float* __restrict__ W4,
    unsigned short* __restrict__ P2, unsigned short* __restrict__ P3, unsigned short* __restrict__ P4) {
  int u = blockIdx.x * 256 + threadIdx.x;   // us8-unit id
  const int U2 = 32000, U3 = 128000;        // 125*CIN*COUT/8 per level
  const float* W; unsigned short* P; int CIN, COUT;
  if (u < U2)           { W = W2; P = P2; CIN = 32;  COUT = 64;  }
  else if (u < U2 + U3) { u -= U2; W = W3; P = P3; CIN = 64;  COUT = 128; }
  else                  { u -= U2 + U3; W = W4; P = P4; CIN = 128; COUT = 256; }
  int MAT8 = CIN * COUT / 8;
  int k = u / MAT8, off8 = u % MAT8;
  int g = off8 & 3;
  int rem = off8 >> 2;
  int n = rem % COUT, kb = rem / COUT;
  const float* ws = W + ((size_t)k * CIN + kb * 32 + g * 8) * COUT + n;
  us8 o;
#pragma unroll
  for (int j = 0; j < 8; ++j) o[j] = to_bf16(ws[(size_t)j * COUT]);
  *(us8*)(P + (size_t)u * 8) = o;
}

// ---------- fused prep: count(L2..L4) ∪ conv1 (coalesced 32-per-edge atomics) ----------
__global__ __launch_bounds__(256) void sc_prep(
    const int* __restrict__ ei2, const float* __restrict__ ps2,
    const int* __restrict__ ei3, const float* __restrict__ ps3,
    const int* __restrict__ ei4, const float* __restrict__ ps4,
    unsigned* __restrict__ bc2, unsigned* __restrict__ bc3, unsigned* __restrict__ bc4,
    unsigned* __restrict__ deg2, unsigned* __restrict__ deg3, unsigned* __restrict__ deg4,
    const float* __restrict__ x, const int* __restrict__ ei1, const float* __restrict__ ps1,
    const float* __restrict__ W1, float* __restrict__ agg1, unsigned* __restrict__ deg1) {
  __shared__ unsigned hist[64];
  int b = blockIdx.x, t = threadIdx.x;
  if (b < 336) {  // count arm (256 edges/block)
    const int* ei; const float* ps; unsigned *bc, *deg; int E, blk, NB;
    if (b < 256)      { ei = ei2; ps = ps2; bc = bc2; deg = deg2; E = 65536; blk = b;       NB = 256; }
    else if (b < 320) { ei = ei3; ps = ps3; bc = bc3; deg = deg3; E = 16384; blk = b - 256; NB = 64;  }
    else              { ei = ei4; ps = ps4; bc = bc4; deg = deg4; E = 4096;  blk = b - 320; NB = 16;  }
    if (t < 64) hist[t] = 0;
    __syncthreads();
    int e = blk * 256 + t;
    atomicAdd(&hist[cell_of(ps, e)], 1u);
    atomicAdd(deg + ei[E + e], 1u);
    __syncthreads();
    if (t < 64) bc[(size_t)t * NB + blk] = hist[t];
    return;
  }
  b -= 336;
  // conv1 arm: 32768 blocks, 2 edges per wave; basis deduped via shuffles
  int tid = b * 256 + t;
  int e = tid >> 5, o = tid & 31;
  int ebit = t & 32;  // wave-half of this edge
  int src = ei1[e], dst = ei1[262144 + e];
  float f[3]; int lo[3];
#pragma unroll
  for (int d = 0; d < 3; ++d) {
    float v = ps1[e * 3 + d] * 4.0f;
    float fl = fminf(fmaxf(floorf(v), 0.0f), 3.0f);
    lo[d] = (int)fl;
    f[d] = v - fl;
  }
  // own corner (meaningful for o<8)
  int so = o & 7;
  int c0 = so & 1, c1 = (so >> 1) & 1, c2 = (so >> 2) & 1;
  float bw_own = (c0 ? f[0] : 1.0f - f[0]) * (c1 ? f[1] : 1.0f - f[1]) *
                 (c2 ? f[2] : 1.0f - f[2]);
  int k_own = (lo[0] + c0) + 5 * (lo[1] + c1) + 25 * (lo[2] + c2);
  float acc = 0.f;
#pragma unroll
  for (int s = 0; s < 8; ++s) {
    float bws = __shfl(bw_own, ebit + s);
    int ks = __shfl(k_own, ebit + s);
    acc += bws * W1[ks * 32 + o];
  }
  atomicAdd(agg1 + dst * 32 + o, x[src] * acc);
  if (o == 0) atomicAdd(deg1 + dst, 1u);
}

// ---------- scan: hierarchical, 1 block x 1024 threads ----------
__global__ __launch_bounds__(1024) void sc_scan_all(
    const unsigned* __restrict__ bc2, const unsigned* __restrict__ bc3,
    const unsigned* __restrict__ bc4,
    unsigned* __restrict__ bb2, unsigned* __restrict__ bb3, unsigned* __restrict__ bb4,
    unsigned* __restrict__ cnt2, unsigned* __restrict__ cnt3, unsigned* __restrict__ cnt4,
    unsigned* __restrict__ base2, unsigned* __restrict__ base3, unsigned* __restrict__ base4,
    unsigned* __restrict__ wt2, unsigned* __restrict__ wt3, unsigned* __restrict__ wt4) {
  __shared__ unsigned tot[3][64];
  __shared__ unsigned sbs[3][64];
  int t = threadIdx.x, w = t >> 6, lane = t & 63;
  // ---- phase 1: 16 waves, intra-cell block prefixes + cell totals ----
#pragma unroll
  for (int lvl = 0; lvl < 3; ++lvl) {
    const unsigned* bc = lvl == 0 ? bc2 : lvl == 1 ? bc3 : bc4;
    unsigned* bb = lvl == 0 ? bb2 : lvl == 1 ? bb3 : bb4;
    int NB = lvl == 0 ? 256 : lvl == 1 ? 64 : 16;
    for (int c = w; c < 64; c += 16) {
      unsigned cellsum = 0;
      for (int sub = 0; sub * 64 < NB; ++sub) {
        int bi = sub * 64 + lane;
        unsigned v = (bi < NB) ? bc[c * NB + bi] : 0u;
        int incl = (int)v;
#pragma unroll
        for (int d = 1; d < 64; d <<= 1) {
          int tv = __shfl_up(incl, d);
          if (lane >= d) incl += tv;
        }
        if (bi < NB) bb[c * NB + bi] = cellsum + (unsigned)incl - v;
        cellsum += (unsigned)__shfl(incl, 63);
      }
      if (lane == 0) tot[lvl][c] = cellsum;
    }
  }
  __syncthreads();
  // ---- phase 2: per-level 64-cell scan + work table ----
  if (w < 3) {
    unsigned* cnt = w == 0 ? cnt2 : w == 1 ? cnt3 : cnt4;
    unsigned* bs  = w == 0 ? base2 : w == 1 ? base3 : base4;
    unsigned* wt  = w == 0 ? wt2 : w == 1 ? wt3 : wt4;
    int NSP  = w == 0 ? 1 : w == 1 ? 2 : 4;
    int MAXW = w == 0 ? MAXW2 : w == 1 ? MAXW3 : MAXW4;
    unsigned v = tot[w][lane];
    int incl = (int)v;
#pragma unroll
    for (int d = 1; d < 64; d <<= 1) {
      int tv = __shfl_up(incl, d);
      if (lane >= d) incl += tv;
    }
    unsigned excl = (unsigned)incl - v;
    sbs[w][lane] = excl;
    cnt[lane] = v;
    bs[lane] = excl;
    int nch = (int)((v + 63) >> 6);
    int cscan = nch;
#pragma unroll
    for (int d = 1; d < 64; d <<= 1) {
      int tv = __shfl_up(cscan, d);
      if (lane >= d) cscan += tv;
    }
    int cbase = cscan - nch;
    int CT = __shfl(cscan, 63);
    for (int ch = 0; ch < nch; ++ch)
      for (int ns = 0; ns < NSP; ++ns)
        wt[(cbase + ch) * NSP + ns] = ((unsigned)lane << 16) | ((unsigned)ch << 8) | (unsigned)ns;
    for (int i = CT * NSP + lane; i < MAXW; i += 64) wt[i] = 0xFFFFFFFFu;
  }
  __syncthreads();
  // ---- phase 3: add cell base into bb ----
  for (int i = t; i < 64 * 256; i += 1024) bb2[i] += sbs[0][i >> 8];
  for (int i = t; i < 64 * 64; i += 1024)  bb3[i] += sbs[1][i >> 6];
  for (int i = t; i < 64 * 16; i += 1024)  bb4[i] += sbs[2][i >> 4];
}

// ---------- fused rank(L2..L4) ∪ finpool level-1 ----------
__global__ __launch_bounds__(256) void sc_rank_fin1(
    const int* __restrict__ ei2, const float* __restrict__ ps2,
    const int* __restrict__ ei3, const float* __restrict__ ps3,
    const int* __restrict__ ei4, const float* __restrict__ ps4,
    const unsigned* __restrict__ bb2, const unsigned* __restrict__ bb3,
    const unsigned* __restrict__ bb4,
    int* __restrict__ eid2, int* __restrict__ eid3, int* __restrict__ eid4,
    int* __restrict__ dst2, int* __restrict__ dst3, int* __restrict__ dst4,
    const float* __restrict__ x, const float* __restrict__ agg1,
    const unsigned* __restrict__ deg1, const float* __restrict__ root1,
    const float* __restrict__ b1, const int* __restrict__ cl1,
    unsigned* __restrict__ pe1) {
  __shared__ unsigned hist[64];
  int b = blockIdx.x, t = threadIdx.x;
  if (b < 336) {  // rank arm (mirrors sc_prep count-arm block mapping)
    const int* ei; const float* ps; const unsigned* bb; int *eid, *dsts; int E, blk, NB;
    if (b < 256)      { ei = ei2; ps = ps2; bb = bb2; eid = eid2; dsts = dst2; E = 65536; blk = b;       NB = 256; }
    else if (b < 320) { ei = ei3; ps = ps3; bb = bb3; eid = eid3; dsts = dst3; E = 16384; blk = b - 256; NB = 64;  }
    else              { ei = ei4; ps = ps4; bb = bb4; eid = eid4; dsts = dst4; E = 4096;  blk = b - 320; NB = 16;  }
    if (t < 64) hist[t] = 0;
    __syncthreads();
    int e = blk * 256 + t;
    int cell = cell_of(ps, e);
    unsigned r = atomicAdd(&hist[cell], 1u);
    int p = (int)(bb[cell * NB + blk] + r);
    eid[p] = e;
    dsts[p] = ei[E + e];
    return;
  }
  b -= 336;
  // finpool1 arm
  int tid = b * 256 + t;  // over 32768*32
  int n = tid >> 5, o = tid & 31;
  unsigned dv = deg1[n];
  float acc = agg1[tid] / (float)(dv ? dv : 1u) + b1[o] + x[n] * root1[o];
  atomicMax(pe1 + (size_t)cl1[n] * 32 + o, enc_pool(eluf(acc)));
}

// ---------- fused finalize + pool (levels 2..4) ----------
template <int CIN, int COUT>
__global__ void sc_finpool(const unsigned* __restrict__ xenc, const float* __restrict__ agg,
                           const unsigned* __restrict__ deg, const float* __restrict__ root,
                           const float* __restrict__ bias, const int* __restrict__ cluster,
                           unsigned* __restrict__ pe_out, int N) {
  int tid = blockIdx.x * blockDim.x + threadIdx.x;
  if (tid >= N * COUT) return;
  int n = tid / COUT, o = tid % COUT;
  unsigned dv = deg[n];
  float acc = agg[tid] / (float)(dv ? dv : 1u) + bias[o];
#pragma unroll 4
  for (int c = 0; c < CIN; ++c)
    acc += dec_pool(xenc[n * CIN + c]) * root[c * COUT + o];
  atomicMax(pe_out + (size_t)cluster[n] * COUT + o, enc_pool(eluf(acc)));
}

// ---------- GEMM: dense work table, N-split, A-tile built from pe, B staged from Wp ----------
// entry: cell<<16 | chunk<<8 | nslice. Block: 64 rows x 64 cols, full K.
template <int CIN, int COUT, int NSP>
DEVI void gemm_impl(const int* __restrict__ ei, const float* __restrict__ ps,
                    const unsigned* __restrict__ xenc, const int* __restrict__ eid,
                    const unsigned short* __restrict__ Wp,
                    const unsigned* __restrict__ cnt, const unsigned* __restrict__ base,
                    const unsigned* __restrict__ wtab, const int* __restrict__ dsts,
                    float* __restrict__ agg) {
  constexpr int K = 8 * CIN;
  constexpr int NCOL = COUT / NSP;   // 64 for all levels
  constexpr int NT = NCOL / 16;      // 4
  constexpr int UPT = NCOL / 32;     // 2
  constexpr int NPASS = K / 64;
  __shared__ __attribute__((aligned(16))) unsigned char lds[2 * NCOL * 80];
  __shared__ __attribute__((aligned(16))) unsigned short ldsA[64][72];
  __shared__ float s_bw[64][8];
  __shared__ int s_src[64];
  unsigned u = wtab[blockIdx.x];
  if (u == 0xFFFFFFFFu) return;
  int cell = u >> 16, chunk = (u >> 8) & 255, nsl = u & 255;
  int n0 = nsl * NCOL;
  int m = (int)cnt[cell], cb = (int)base[cell];
  int row0 = chunk * 64;
  int tid = threadIdx.x;
  int wv = tid >> 6, lane = tid & 63, g4 = lane >> 4, ln = lane & 15;
  int lo0 = cell & 3, lo1 = (cell >> 2) & 3, lo2 = cell >> 4;
  // block init: per-row edge basis + src (64 rows, clamped)
  if (tid < 64) {
    int ridx = cb + min(row0 + tid, m - 1);
    int e = eid[ridx];
    s_src[tid] = ei[e];
    float f[3];
#pragma unroll
    for (int d = 0; d < 3; ++d) {
      float v = ps[e * 3 + d] * 4.0f;
      float fl = fminf(fmaxf(floorf(v), 0.0f), 3.0f);
      f[d] = v - fl;
    }
#pragma unroll
    for (int s = 0; s < 8; ++s) {
      int b0 = s & 1, b1 = (s >> 1) & 1, b2 = (s >> 2) & 1;
      s_bw[tid][s] = (b0 ? f[0] : 1.0f - f[0]) * (b1 ? f[1] : 1.0f - f[1]) *
                     (b2 ? f[2] : 1.0f - f[2]);
    }
  }
  f32x4 acc[NT];
#pragma unroll
  for (int t = 0; t < NT; ++t) acc[t] = (f32x4){0.f, 0.f, 0.f, 0.f};
  for (int pass = 0; pass < NPASS; ++pass) {
    int k0 = pass * 64;
    __syncthreads();
    // stage B slice from fragment-ready Wp (one us8 load per unit)
#pragma unroll
    for (int i = 0; i < UPT; ++i) {
      int u16 = tid + i * 256;
      int grp = u16 / (4 * NCOL), win = u16 % (4 * NCOL);
      int kg = k0 + grp * 32;
      int s = kg / CIN, kb = (kg % CIN) >> 5;
      int b0 = s & 1, b1 = (s >> 1) & 1, b2 = (s >> 2) & 1;
      int mat = (lo0 + b0) + 5 * (lo1 + b1) + 25 * (lo2 + b2);
      const us8* srcp = (const us8*)(Wp + (size_t)mat * (CIN * COUT) +
                                     (size_t)(kb * COUT * 4 + n0 * 4 + win) * 8);
      int r = grp * NCOL + (win >> 2), gg = win & 3;
      *(us8*)(lds + r * 80 + gg * 16) = *srcp;
    }
    // stage A tile: 64 rows x 64 k, gathered from pe + bw-scaled
    {
      int r = tid >> 2, q = tid & 3;
      int kg = k0 + q * 16;
      int sidx = kg / CIN;
      int c0 = kg & (CIN - 1);
      float bwv = s_bw[r][sidx];
      const uint4* xp = (const uint4*)(xenc + (size_t)s_src[r] * CIN + c0);
      uint4 xa = xp[0], xb = xp[1];
      us8 o0;
      o0[0] = to_bf16(bwv * dec_pool(xa.x)); o0[1] = to_bf16(bwv * dec_pool(xa.y));
      o0[2] = to_bf16(bwv * dec_pool(xa.z)); o0[3] = to_bf16(bwv * dec_pool(xa.w));
      o0[4] = to_bf16(bwv * dec_pool(xb.x)); o0[5] = to_bf16(bwv * dec_pool(xb.y));
      o0[6] = to_bf16(bwv * dec_pool(xb.z)); o0[7] = to_bf16(bwv * dec_pool(xb.w));
      uint4 xc = xp[2], xd = xp[3];
      us8 o1;
      o1[0] = to_bf16(bwv * dec_pool(xc.x)); o1[1] = to_bf16(bwv * dec_pool(xc.y));
      o1[2] = to_bf16(bwv * dec_pool(xc.z)); o1[3] = to_bf16(bwv * dec_pool(xc.w));
      o1[4] = to_bf16(bwv * dec_pool(xd.x)); o1[5] = to_bf16(bwv * dec_pool(xd.y));
      o1[6] = to_bf16(bwv * dec_pool(xd.z)); o1[7] = to_bf16(bwv * dec_pool(xd.w));
      *(us8*)&ldsA[r][q * 16] = o0;
      *(us8*)&ldsA[r][q * 16 + 8] = o1;
    }
    __syncthreads();
#pragma unroll
    for (int kk = 0; kk < 2; ++kk) {
      bf16x8 af = *(const bf16x8*)&ldsA[wv * 16 + ln][kk * 32 + g4 * 8];
#pragma unroll
      for (int t = 0; t < NT; ++t) {
        int r = kk * NCOL + t * 16 + ln;
        bf16x8 bfr = *(const bf16x8*)(lds + r * 80 + g4 * 16);
        acc[t] = __builtin_amdgcn_mfma_f32_16x16x32_bf16(af, bfr, acc[t], 0, 0, 0);
      }
    }
  }
  int row_b = row0 + wv * 16 + g4 * 4;
  int dstv[4];
#pragma unroll
  for (int r4 = 0; r4 < 4; ++r4)
    dstv[r4] = (row_b + r4 < m) ? dsts[cb + row_b + r4] : -1;
#pragma unroll
  for (int t = 0; t < NT; ++t) {
#pragma unroll
    for (int r4 = 0; r4 < 4; ++r4) {
      if (dstv[r4] >= 0)
        atomicAdd(agg + (size_t)dstv[r4] * COUT + n0 + t * 16 + ln, acc[t][r4]);
    }
  }
}

__global__ __launch_bounds__(256) void sc_gemm_l2(
    const int* ei, const float* ps, const unsigned* xenc, const int* eid,
    const unsigned short* Wp, const unsigned* cnt, const unsigned* base,
    const unsigned* wtab, const int* dsts, float* agg) {
  gemm_impl<32, 64, 1>(ei, ps, xenc, eid, Wp, cnt, base, wtab, dsts, agg);
}
__global__ __launch_bounds__(256) void sc_gemm_l3(
    const int* ei, const float* ps, const unsigned* xenc, const int* eid,
    const unsigned short* Wp, const unsigned* cnt, const unsigned* base,
    const unsigned* wtab, const int* dsts, float* agg) {
  gemm_impl<64, 128, 2>(ei, ps, xenc, eid, Wp, cnt, base, wtab, dsts, agg);
}
__global__ __launch_bounds__(256) void sc_gemm_l4(
    const int* ei, const float* ps, const unsigned* xenc, const int* eid,
    const unsigned short* Wp, const unsigned* cnt, const unsigned* base,
    const unsigned* wtab, const int* dsts, float* agg) {
  gemm_impl<128, 256, 4>(ei, ps, xenc, eid, Wp, cnt, base, wtab, dsts, agg);
}

// ---------- FC head ----------
__global__ void sc_fc1(const unsigned* __restrict__ xenc, const float* __restrict__ w,
                       float* __restrict__ out) {
  __shared__ float sx[8][32];
  int t = threadIdx.x;
  int j = blockIdx.x * 256 + t;          // 0..511
  int c0 = blockIdx.y * 32;              // 64 chunks
  {
    int b = t >> 5, c = t & 31;
    sx[b][c] = dec_pool(xenc[b * 2048 + c0 + c]);
  }
  __syncthreads();
  float acc[8];
#pragma unroll
  for (int b = 0; b < 8; ++b) acc[b] = 0.f;
#pragma unroll 4
  for (int cc = 0; cc < 32; ++cc) {
    float wv = w[(size_t)(c0 + cc) * 512 + j];
#pragma unroll
    for (int b = 0; b < 8; ++b) acc[b] += sx[b][cc] * wv;
  }
#pragma unroll
  for (int b = 0; b < 8; ++b) atomicAdd(out + b * 512 + j, acc[b]);
}

__global__ void sc_fc2(const float* __restrict__ h, const float* __restrict__ b1,
                       const float* __restrict__ w2, const float* __restrict__ b2,
                       float* __restrict__ out) {
  int b = blockIdx.x;
  int lane = threadIdx.x;
  float part[10];
#pragma unroll
  for (int o = 0; o < 10; ++o) part[o] = 0.f;
  for (int k = 0; k < 8; ++k) {
    int c = k * 64 + lane;
    float v = eluf(h[b * 512 + c] + b1[c]);
#pragma unroll
    for (int o = 0; o < 10; ++o) part[o] += v * w2[c * 10 + o];
  }
#pragma unroll
  for (int o = 0; o < 10; ++o) {
#pragma unroll
    for (int d = 32; d > 0; d >>= 1) part[o] += __shfl_down(part[o], d);
  }
  if (lane == 0) {
    float z[10], mx = -1e30f;
#pragma unroll
    for (int o = 0; o < 10; ++o) { z[o] = part[o] + b2[o]; mx = fmaxf(mx, z[o]); }
    float sum = 0.f;
#pragma unroll
    for (int o = 0; o < 10; ++o) sum += expf(z[o] - mx);
    float lse = mx + logf(sum);
#pragma unroll
    for (int o = 0; o < 10; ++o) out[b * 10 + o] = z[o] - lse;
  }
}

// ---------- host ----------
extern "C" void kernel_launch(void* const* d_in, const int* in_sizes, int n_in,
                              void* d_out, int out_size, void* d_ws, size_t ws_size,
                              hipStream_t stream) {
  (void)in_sizes; (void)n_in; (void)out_size; (void)ws_size;
  const float* x    = (const float*)d_in[0];
  const int*   ei1  = (const int*)d_in[1];
  const float* ps1  = (const float*)d_in[2];
  const int*   cl1  = (const int*)d_in[3];
  const int*   ei2  = (const int*)d_in[4];
  const float* ps2  = (const float*)d_in[5];
  const int*   cl2  = (const int*)d_in[6];
  const int*   ei3  = (const int*)d_in[7];
  const float* ps3  = (const float*)d_in[8];
  const int*   cl3  = (const int*)d_in[9];
  const int*   ei4  = (const int*)d_in[10];
  const float* ps4  = (const float*)d_in[11];
  const int*   cl4  = (const int*)d_in[12];
  const float* W1   = (const float*)d_in[13];
  const float* root1= (const float*)d_in[14];
  const float* b1   = (const float*)d_in[15];
  const float* W2   = (const float*)d_in[16];
  const float* root2= (const float*)d_in[17];
  const float* b2   = (const float*)d_in[18];
  const float* W3   = (const float*)d_in[19];
  const float* root3= (const float*)d_in[20];
  const float* b3   = (const float*)d_in[21];
  const float* W4   = (const float*)d_in[22];
  const float* root4= (const float*)d_in[23];
  const float* b4   = (const float*)d_in[24];
  const float* fc1w = (const float*)d_in[25];
  const float* fc1b = (const float*)d_in[26];
  const float* fc2w = (const float*)d_in[27];
  const float* fc2b = (const float*)d_in[28];
  float* out = (float*)d_out;

  char* ws = (char*)d_ws;
  size_t off = 0;
  auto alloc = [&](size_t bytes) -> void* {
    void* p = ws + off;
    off = (off + bytes + 255) & ~(size_t)255;
    return p;
  };
  // ---- zero-init region (one memset) ----
  float*    agg1 = (float*)alloc(32768ull * 32 * 4);
  float*    agg2 = (float*)alloc(8192ull * 64 * 4);
  float*    agg3 = (float*)alloc(2048ull * 128 * 4);
  float*    agg4 = (float*)alloc(512ull * 256 * 4);
  unsigned* deg1 = (unsigned*)alloc(32768ull * 4);
  unsigned* deg2 = (unsigned*)alloc(8192ull * 4);
  unsigned* deg3 = (unsigned*)alloc(2048ull * 4);
  unsigned* deg4 = (unsigned*)alloc(512ull * 4);
  unsigned* pe1  = (unsigned*)alloc(8192ull * 32 * 4);
  unsigned* pe2  = (unsigned*)alloc(2048ull * 64 * 4);
  unsigned* pe3  = (unsigned*)alloc(512ull * 128 * 4);
  unsigned* pe4  = (unsigned*)alloc(64ull * 256 * 4);
  float*    fc1o = (float*)alloc(8ull * 512 * 4);
  size_t zero_bytes = off;
  // ---- non-zero region (fully written each call) ----
  unsigned* bc2   = (unsigned*)alloc(64ull * 256 * 4);
  unsigned* bc3   = (unsigned*)alloc(64ull * 64 * 4);
  unsigned* bc4   = (unsigned*)alloc(64ull * 16 * 4);
  unsigned* bb2   = (unsigned*)alloc(64ull * 256 * 4);
  unsigned* bb3   = (unsigned*)alloc(64ull * 64 * 4);
  unsigned* bb4   = (unsigned*)alloc(64ull * 16 * 4);
  unsigned* cnt2  = (unsigned*)alloc(64 * 4);
  unsigned* cnt3  = (unsigned*)alloc(64 * 4);
  unsigned* cnt4  = (unsigned*)alloc(64 * 4);
  unsigned* base2 = (unsigned*)alloc(64 * 4);
  unsigned* base3 = (unsigned*)alloc(64 * 4);
  unsigned* base4 = (unsigned*)alloc(64 * 4);
  unsigned* wt2   = (unsigned*)alloc(MAXW2 * 4);
  unsigned* wt3   = (unsigned*)alloc(MAXW3 * 4);
  unsigned* wt4   = (unsigned*)alloc(MAXW4 * 4);
  int* eid2 = (int*)alloc(65536ull * 4);
  int* eid3 = (int*)alloc(16384ull * 4);
  int* eid4 = (int*)alloc(4096ull * 4);
  int* dst2 = (int*)alloc(65536ull * 4);
  int* dst3 = (int*)alloc(16384ull * 4);
  int* dst4 = (int*)alloc(4096ull * 4);
  unsigned short* Wp2 = (unsigned short*)alloc(125ull * 32 * 64 * 2);
  unsigned short* Wp3 = (unsigned short*)alloc(125ull * 64 * 128 * 2);
  unsigned short* Wp4 = (unsigned short*)alloc(125ull * 128 * 256 * 2);

  hipMemsetAsync(d_ws, 0, zero_bytes, stream);
  // fragment-ready bf16 weights (672000 us8 units)
  sc_convw<<<2625, 256, 0, stream>>>(W2, W3, W4, Wp2, Wp3, Wp4);
  // prep: count ∪ conv1  (336 + 32768 blocks)
  sc_prep<<<33104, 256, 0, stream>>>(ei2, ps2, ei3, ps3, ei4, ps4,
                                     bc2, bc3, bc4, deg2, deg3, deg4,
                                     x, ei1, ps1, W1, agg1, deg1);
  sc_scan_all<<<1, 1024, 0, stream>>>(bc2, bc3, bc4, bb2, bb3, bb4,
                                      cnt2, cnt3, cnt4, base2, base3, base4,
                                      wt2, wt3, wt4);
  // rank ∪ finpool1  (336 + 4096 blocks)
  sc_rank_fin1<<<4432, 256, 0, stream>>>(ei2, ps2, ei3, ps3, ei4, ps4,
                                         bb2, bb3, bb4, eid2, eid3, eid4,
                                         dst2, dst3, dst4,
                                         x, agg1, deg1, root1, b1, cl1, pe1);

  // ---- level 2 ----
  sc_gemm_l2<<<MAXW2, 256, 0, stream>>>(ei2, ps2, pe1, eid2, Wp2, cnt2, base2, wt2, dst2, agg2);
  sc_finpool<32, 64><<<2048, 256, 0, stream>>>(pe1, agg2, deg2, root2, b2, cl2, pe2, 8192);

  // ---- level 3 ----
  sc_gemm_l3<<<MAXW3, 256, 0, stream>>>(ei3, ps3, pe2, eid3, Wp3, cnt3, base3, wt3, dst3, agg3);
  sc_finpool<64, 128><<<1024, 256, 0, stream>>>(pe2, agg3, deg3, root3, b3, cl3, pe3, 2048);

  // ---- level 4 ----
  sc_gemm_l4<<<MAXW4, 256, 0, stream>>>(ei4, ps4, pe3, eid4, Wp4, cnt4, base4, wt4, dst4, agg4);
  sc_finpool<128, 256><<<512, 256, 0, stream>>>(pe3, agg4, deg4, root4, b4, cl4, pe4, 512);

  // ---- FC head ----
  sc_fc1<<<dim3(2, 64), 256, 0, stream>>>(pe4, fc1w, fc1o);
  sc_fc2<<<8, 64, 0, stream>>>(fc1o, fc1b, fc2w, fc2b, out);
}